// Round 1
// baseline (302.998 us; speedup 1.0000x reference)
//
#include <hip/hip_runtime.h>
#include <hip/hip_bf16.h>

typedef __attribute__((ext_vector_type(8))) short short8;
typedef __attribute__((ext_vector_type(4))) float f32x4;

#define NROWS 8192
#define DDIM  64

// ---------- bf16 split helpers (RNE) ----------
__device__ __forceinline__ unsigned short f32_to_bf16_bits(float f) {
    unsigned u = __float_as_uint(f);
    unsigned r = u + 0x7FFFu + ((u >> 16) & 1u);
    return (unsigned short)(r >> 16);
}
__device__ __forceinline__ float bf16_bits_to_f32(unsigned short b) {
    return __uint_as_float(((unsigned)b) << 16);
}

// ---------- kernel 1: split f32 -> bf16 hi/lo + row squared norms ----------
__global__ __launch_bounds__(256) void prep_kernel(
    const float* __restrict__ x, const float* __restrict__ y,
    short* __restrict__ xh, short* __restrict__ xl,
    short* __restrict__ yh, short* __restrict__ yl,
    float* __restrict__ xsq, float* __restrict__ ysq)
{
    int gwid = (int)((blockIdx.x * blockDim.x + threadIdx.x) >> 6); // one wave per row
    int lane = threadIdx.x & 63;

    const float* src; short* dh; short* dl; float* dsq; int row;
    if (gwid < NROWS) { src = x; dh = xh; dl = xl; dsq = xsq; row = gwid; }
    else              { src = y; dh = yh; dl = yl; dsq = ysq; row = gwid - NROWS; }

    float v = src[row * DDIM + lane];          // DDIM==64 == wave size
    unsigned short hb = f32_to_bf16_bits(v);
    float hf = bf16_bits_to_f32(hb);
    unsigned short lb = f32_to_bf16_bits(v - hf);   // exact residual, then RNE

    dh[row * DDIM + lane] = (short)hb;
    dl[row * DDIM + lane] = (short)lb;

    float sq = v * v;
    #pragma unroll
    for (int off = 32; off; off >>= 1) sq += __shfl_xor(sq, off);
    if (lane == 0) dsq[row] = sq;
}

// ---------- kernel 2: MFMA GEMM + RBF epilogue (bf16x3 split) ----------
// 128x128 tile per block, 4 waves in 2x2, each wave a 64x64 quadrant.
__global__ __launch_bounds__(256) void rbf_mfma_kernel(
    const short* __restrict__ xh, const short* __restrict__ xl,
    const short* __restrict__ yh, const short* __restrict__ yl,
    const float* __restrict__ xsq, const float* __restrict__ ysq,
    float* __restrict__ out)
{
    int bid = blockIdx.x;
    int bi = bid >> 6;          // 64 tiles along x-rows
    int bj = bid & 63;          // 64 tiles along y-rows
    int tid = threadIdx.x;
    int wid = tid >> 6, lane = tid & 63;
    int wr = wid >> 1, wc = wid & 1;
    int g = lane >> 4, l15 = lane & 15;

    int arow = bi * 128 + wr * 64 + l15;   // + mf*16
    int brow = bj * 128 + wc * 64 + l15;   // + nf*16

    f32x4 acc[4][4];
    #pragma unroll
    for (int i = 0; i < 4; ++i)
        #pragma unroll
        for (int j = 0; j < 4; ++j)
            acc[i][j] = (f32x4){0.f, 0.f, 0.f, 0.f};

    #pragma unroll
    for (int ks = 0; ks < 2; ++ks) {
        int koff = ks * 32 + g * 8;
        short8 ah[4], al[4], bh[4], bl[4];
        #pragma unroll
        for (int f = 0; f < 4; ++f) {
            long aoff = (long)(arow + f * 16) * DDIM + koff;
            long boff = (long)(brow + f * 16) * DDIM + koff;
            ah[f] = *(const short8*)(xh + aoff);
            al[f] = *(const short8*)(xl + aoff);
            bh[f] = *(const short8*)(yh + boff);
            bl[f] = *(const short8*)(yl + boff);
        }
        #pragma unroll
        for (int mf = 0; mf < 4; ++mf)
            #pragma unroll
            for (int nf = 0; nf < 4; ++nf) {
                acc[mf][nf] = __builtin_amdgcn_mfma_f32_16x16x32_bf16(ah[mf], bh[nf], acc[mf][nf], 0, 0, 0);
                acc[mf][nf] = __builtin_amdgcn_mfma_f32_16x16x32_bf16(ah[mf], bl[nf], acc[mf][nf], 0, 0, 0);
                acc[mf][nf] = __builtin_amdgcn_mfma_f32_16x16x32_bf16(al[mf], bh[nf], acc[mf][nf], 0, 0, 0);
            }
    }

    // epilogue: C/D layout col=lane&15, row=(lane>>4)*4+reg  [measured m89]
    #pragma unroll
    for (int mf = 0; mf < 4; ++mf) {
        #pragma unroll
        for (int r = 0; r < 4; ++r) {
            int m = bi * 128 + wr * 64 + mf * 16 + g * 4 + r;
            float xs = xsq[m];
            #pragma unroll
            for (int nf = 0; nf < 4; ++nf) {
                int n = bj * 128 + wc * 64 + nf * 16 + l15;
                float s = xs + ysq[n] - 2.0f * acc[mf][nf][r];
                s = fmaxf(s, 0.0f);
                out[(long)m * NROWS + n] = __expf(-s);
            }
        }
    }
}

// ---------- fallback: fully fused (no workspace needed) ----------
__global__ __launch_bounds__(256) void rbf_fused_kernel(
    const float* __restrict__ x, const float* __restrict__ y,
    float* __restrict__ out)
{
    int bid = blockIdx.x;
    int bi = bid >> 6, bj = bid & 63;
    int tid = threadIdx.x;
    int wid = tid >> 6, lane = tid & 63;
    int wr = wid >> 1, wc = wid & 1;
    int g = lane >> 4, l15 = lane & 15;

    int abase = bi * 128 + wr * 64;
    int bbase = bj * 128 + wc * 64;

    // per-lane row sums: lane owns row abase+lane / bbase+lane
    float xs_own = 0.f, ys_own = 0.f;
    {
        const float4* px = (const float4*)(x + (long)(abase + lane) * DDIM);
        const float4* py = (const float4*)(y + (long)(bbase + lane) * DDIM);
        #pragma unroll
        for (int i = 0; i < 16; ++i) {
            float4 v = px[i];
            xs_own += v.x * v.x + v.y * v.y + v.z * v.z + v.w * v.w;
            float4 w = py[i];
            ys_own += w.x * w.x + w.y * w.y + w.z * w.z + w.w * w.w;
        }
    }

    f32x4 acc[4][4];
    #pragma unroll
    for (int i = 0; i < 4; ++i)
        #pragma unroll
        for (int j = 0; j < 4; ++j)
            acc[i][j] = (f32x4){0.f, 0.f, 0.f, 0.f};

    #pragma unroll
    for (int ks = 0; ks < 2; ++ks) {
        int koff = ks * 32 + g * 8;
        short8 ah[4], al[4], bh[4], bl[4];
        #pragma unroll
        for (int f = 0; f < 4; ++f) {
            const float* pa = x + (long)(abase + f * 16 + l15) * DDIM + koff;
            const float* pb = y + (long)(bbase + f * 16 + l15) * DDIM + koff;
            #pragma unroll
            for (int i = 0; i < 8; ++i) {
                float va = pa[i];
                unsigned short hba = f32_to_bf16_bits(va);
                ah[f][i] = (short)hba;
                al[f][i] = (short)f32_to_bf16_bits(va - bf16_bits_to_f32(hba));
                float vb = pb[i];
                unsigned short hbb = f32_to_bf16_bits(vb);
                bh[f][i] = (short)hbb;
                bl[f][i] = (short)f32_to_bf16_bits(vb - bf16_bits_to_f32(hbb));
            }
        }
        #pragma unroll
        for (int mf = 0; mf < 4; ++mf)
            #pragma unroll
            for (int nf = 0; nf < 4; ++nf) {
                acc[mf][nf] = __builtin_amdgcn_mfma_f32_16x16x32_bf16(ah[mf], bh[nf], acc[mf][nf], 0, 0, 0);
                acc[mf][nf] = __builtin_amdgcn_mfma_f32_16x16x32_bf16(ah[mf], bl[nf], acc[mf][nf], 0, 0, 0);
                acc[mf][nf] = __builtin_amdgcn_mfma_f32_16x16x32_bf16(al[mf], bh[nf], acc[mf][nf], 0, 0, 0);
            }
    }

    #pragma unroll
    for (int mf = 0; mf < 4; ++mf) {
        #pragma unroll
        for (int r = 0; r < 4; ++r) {
            int m_rel = mf * 16 + g * 4 + r;
            float xs = __shfl(xs_own, m_rel);
            int m = abase + m_rel;
            #pragma unroll
            for (int nf = 0; nf < 4; ++nf) {
                int n_rel = nf * 16 + l15;
                float ys = __shfl(ys_own, n_rel);
                int n = bbase + n_rel;
                float s = xs + ys - 2.0f * acc[mf][nf][r];
                s = fmaxf(s, 0.0f);
                out[(long)m * NROWS + n] = __expf(-s);
            }
        }
    }
}

extern "C" void kernel_launch(void* const* d_in, const int* in_sizes, int n_in,
                              void* d_out, int out_size, void* d_ws, size_t ws_size,
                              hipStream_t stream) {
    const float* x = (const float*)d_in[0];
    const float* y = (const float*)d_in[1];
    float* out = (float*)d_out;

    const size_t plane = (size_t)NROWS * DDIM * sizeof(short); // 1 MB per bf16 plane
    const size_t sqsz  = (size_t)NROWS * sizeof(float);        // 32 KB
    const size_t need  = 4 * plane + 2 * sqsz;                 // ~4.06 MB

    if (ws_size >= need && d_ws != nullptr) {
        char* ws = (char*)d_ws;
        short* xh = (short*)(ws);
        short* xl = (short*)(ws + plane);
        short* yh = (short*)(ws + 2 * plane);
        short* yl = (short*)(ws + 3 * plane);
        float* xsq = (float*)(ws + 4 * plane);
        float* ysq = (float*)(ws + 4 * plane + sqsz);

        // 2*8192 rows, one wave each, 4 waves/block
        prep_kernel<<<(2 * NROWS) / 4, 256, 0, stream>>>(x, y, xh, xl, yh, yl, xsq, ysq);
        rbf_mfma_kernel<<<64 * 64, 256, 0, stream>>>(xh, xl, yh, yl, xsq, ysq, out);
    } else {
        rbf_fused_kernel<<<64 * 64, 256, 0, stream>>>(x, y, out);
    }
}

// Round 6
// 300.627 us; speedup vs baseline: 1.0079x; 1.0079x over previous
//
#include <hip/hip_runtime.h>
#include <hip/hip_bf16.h>

typedef __attribute__((ext_vector_type(8))) short short8;
typedef __attribute__((ext_vector_type(4))) float f32x4;

#define NROWS 8192
#define DDIM  64

#if defined(__has_builtin) && __has_builtin(__builtin_amdgcn_exp2f)
#define FAST_EXP2(x) __builtin_amdgcn_exp2f(x)
#else
#define FAST_EXP2(x) exp2f(x)
#endif

#define LOG2E 1.4426950408889634f

// ---------- bf16 split helpers (RNE) ----------
__device__ __forceinline__ unsigned short f32_to_bf16_bits(float f) {
    unsigned u = __float_as_uint(f);
    unsigned r = u + 0x7FFFu + ((u >> 16) & 1u);
    return (unsigned short)(r >> 16);
}
__device__ __forceinline__ float bf16_bits_to_f32(unsigned short b) {
    return __uint_as_float(((unsigned)b) << 16);
}

// ---------- kernel 1: split f32 -> bf16 hi/lo + scaled row squared norms ----------
// Stores xsl = log2e * ||x_i||^2 so the epilogue is a single fma + exp2.
__global__ __launch_bounds__(256) void prep_kernel(
    const float* __restrict__ x, const float* __restrict__ y,
    short* __restrict__ xh, short* __restrict__ xl,
    short* __restrict__ yh, short* __restrict__ yl,
    float* __restrict__ xsl, float* __restrict__ ysl)
{
    int gwid = (int)((blockIdx.x * blockDim.x + threadIdx.x) >> 6); // one wave per row
    int lane = threadIdx.x & 63;

    const float* src; short* dh; short* dl; float* dsq; int row;
    if (gwid < NROWS) { src = x; dh = xh; dl = xl; dsq = xsl; row = gwid; }
    else              { src = y; dh = yh; dl = yl; dsq = ysl; row = gwid - NROWS; }

    float v = src[row * DDIM + lane];          // DDIM==64 == wave size
    unsigned short hb = f32_to_bf16_bits(v);
    float hf = bf16_bits_to_f32(hb);
    unsigned short lb = f32_to_bf16_bits(v - hf);   // exact residual, then RNE

    dh[row * DDIM + lane] = (short)hb;
    dl[row * DDIM + lane] = (short)lb;

    float sq = v * v;
    #pragma unroll
    for (int off = 32; off; off >>= 1) sq += __shfl_xor(sq, off);
    if (lane == 0) dsq[row] = sq * LOG2E;
}

// ---------- kernel 2: MFMA GEMM + RBF epilogue (bf16x3 split) ----------
// 128x128 tile per block, 4 waves in 2x2, each wave a 64x64 quadrant.
// out = exp2( min( 2*log2e*cross - (xsl + ysl), 0 ) )  ==  exp(-max(s,0))
__global__ __launch_bounds__(256) void rbf_mfma_kernel(
    const short* __restrict__ xh, const short* __restrict__ xl,
    const short* __restrict__ yh, const short* __restrict__ yl,
    const float* __restrict__ xsl, const float* __restrict__ ysl,
    float* __restrict__ out)
{
    int bid = blockIdx.x;
    int bi = bid >> 6;          // 64 tiles along x-rows
    int bj = bid & 63;          // 64 tiles along y-rows
    int tid = threadIdx.x;
    int wid = tid >> 6, lane = tid & 63;
    int wr = wid >> 1, wc = wid & 1;
    int g = lane >> 4, l15 = lane & 15;

    int arow = bi * 128 + wr * 64 + l15;   // + mf*16
    int brow = bj * 128 + wc * 64 + l15;   // + nf*16

    f32x4 acc[4][4];
    #pragma unroll
    for (int i = 0; i < 4; ++i)
        #pragma unroll
        for (int j = 0; j < 4; ++j)
            acc[i][j] = (f32x4){0.f, 0.f, 0.f, 0.f};

    #pragma unroll
    for (int ks = 0; ks < 2; ++ks) {
        int koff = ks * 32 + g * 8;
        short8 ah[4], al[4], bh[4], bl[4];
        #pragma unroll
        for (int f = 0; f < 4; ++f) {
            long aoff = (long)(arow + f * 16) * DDIM + koff;
            long boff = (long)(brow + f * 16) * DDIM + koff;
            ah[f] = *(const short8*)(xh + aoff);
            al[f] = *(const short8*)(xl + aoff);
            bh[f] = *(const short8*)(yh + boff);
            bl[f] = *(const short8*)(yl + boff);
        }
        #pragma unroll
        for (int mf = 0; mf < 4; ++mf)
            #pragma unroll
            for (int nf = 0; nf < 4; ++nf) {
                acc[mf][nf] = __builtin_amdgcn_mfma_f32_16x16x32_bf16(ah[mf], bh[nf], acc[mf][nf], 0, 0, 0);
                acc[mf][nf] = __builtin_amdgcn_mfma_f32_16x16x32_bf16(ah[mf], bl[nf], acc[mf][nf], 0, 0, 0);
                acc[mf][nf] = __builtin_amdgcn_mfma_f32_16x16x32_bf16(al[mf], bh[nf], acc[mf][nf], 0, 0, 0);
            }
    }

    // hoist ysl for this wave's 64 columns: 4 values per lane (one per nf)
    float ysl_r[4];
    #pragma unroll
    for (int nf = 0; nf < 4; ++nf)
        ysl_r[nf] = ysl[bj * 128 + wc * 64 + nf * 16 + l15];

    // epilogue: C/D layout col=lane&15, row=(lane>>4)*4+reg  [measured m89]
    #pragma unroll
    for (int mf = 0; mf < 4; ++mf) {
        #pragma unroll
        for (int r = 0; r < 4; ++r) {
            int m = bi * 128 + wr * 64 + mf * 16 + g * 4 + r;
            float xs = xsl[m];
            float* orow = out + (long)m * NROWS + (bj * 128 + wc * 64 + l15);
            #pragma unroll
            for (int nf = 0; nf < 4; ++nf) {
                float t = __builtin_fmaf(2.0f * LOG2E, acc[mf][nf][r], -(xs + ysl_r[nf]));
                t = fminf(t, 0.0f);           // guard tiny negatives of sq_norm
                __builtin_nontemporal_store(FAST_EXP2(t), orow + nf * 16);
            }
        }
    }
}

// ---------- fallback: fully fused (no workspace needed) ----------
__global__ __launch_bounds__(256) void rbf_fused_kernel(
    const float* __restrict__ x, const float* __restrict__ y,
    float* __restrict__ out)
{
    int bid = blockIdx.x;
    int bi = bid >> 6, bj = bid & 63;
    int tid = threadIdx.x;
    int wid = tid >> 6, lane = tid & 63;
    int wr = wid >> 1, wc = wid & 1;
    int g = lane >> 4, l15 = lane & 15;

    int abase = bi * 128 + wr * 64;
    int bbase = bj * 128 + wc * 64;

    float xs_own = 0.f, ys_own = 0.f;
    {
        const float4* px = (const float4*)(x + (long)(abase + lane) * DDIM);
        const float4* py = (const float4*)(y + (long)(bbase + lane) * DDIM);
        #pragma unroll
        for (int i = 0; i < 16; ++i) {
            float4 v = px[i];
            xs_own += v.x * v.x + v.y * v.y + v.z * v.z + v.w * v.w;
            float4 w = py[i];
            ys_own += w.x * w.x + w.y * w.y + w.z * w.z + w.w * w.w;
        }
    }

    f32x4 acc[4][4];
    #pragma unroll
    for (int i = 0; i < 4; ++i)
        #pragma unroll
        for (int j = 0; j < 4; ++j)
            acc[i][j] = (f32x4){0.f, 0.f, 0.f, 0.f};

    #pragma unroll
    for (int ks = 0; ks < 2; ++ks) {
        int koff = ks * 32 + g * 8;
        short8 ah[4], al[4], bh[4], bl[4];
        #pragma unroll
        for (int f = 0; f < 4; ++f) {
            const float* pa = x + (long)(abase + f * 16 + l15) * DDIM + koff;
            const float* pb = y + (long)(bbase + f * 16 + l15) * DDIM + koff;
            #pragma unroll
            for (int i = 0; i < 8; ++i) {
                float va = pa[i];
                unsigned short hba = f32_to_bf16_bits(va);
                ah[f][i] = (short)hba;
                al[f][i] = (short)f32_to_bf16_bits(va - bf16_bits_to_f32(hba));
                float vb = pb[i];
                unsigned short hbb = f32_to_bf16_bits(vb);
                bh[f][i] = (short)hbb;
                bl[f][i] = (short)f32_to_bf16_bits(vb - bf16_bits_to_f32(hbb));
            }
        }
        #pragma unroll
        for (int mf = 0; mf < 4; ++mf)
            #pragma unroll
            for (int nf = 0; nf < 4; ++nf) {
                acc[mf][nf] = __builtin_amdgcn_mfma_f32_16x16x32_bf16(ah[mf], bh[nf], acc[mf][nf], 0, 0, 0);
                acc[mf][nf] = __builtin_amdgcn_mfma_f32_16x16x32_bf16(ah[mf], bl[nf], acc[mf][nf], 0, 0, 0);
                acc[mf][nf] = __builtin_amdgcn_mfma_f32_16x16x32_bf16(al[mf], bh[nf], acc[mf][nf], 0, 0, 0);
            }
    }

    #pragma unroll
    for (int mf = 0; mf < 4; ++mf) {
        #pragma unroll
        for (int r = 0; r < 4; ++r) {
            int m_rel = mf * 16 + g * 4 + r;
            float xs = __shfl(xs_own, m_rel);
            int m = abase + m_rel;
            #pragma unroll
            for (int nf = 0; nf < 4; ++nf) {
                int n_rel = nf * 16 + l15;
                float ys = __shfl(ys_own, n_rel);
                int n = bbase + n_rel;
                float s = fmaxf(xs + ys - 2.0f * acc[mf][nf][r], 0.0f);
                __builtin_nontemporal_store(__expf(-s), &out[(long)m * NROWS + n]);
            }
        }
    }
}

extern "C" void kernel_launch(void* const* d_in, const int* in_sizes, int n_in,
                              void* d_out, int out_size, void* d_ws, size_t ws_size,
                              hipStream_t stream) {
    const float* x = (const float*)d_in[0];
    const float* y = (const float*)d_in[1];
    float* out = (float*)d_out;

    const size_t plane = (size_t)NROWS * DDIM * sizeof(short); // 1 MB per bf16 plane
    const size_t sqsz  = (size_t)NROWS * sizeof(float);        // 32 KB
    const size_t need  = 4 * plane + 2 * sqsz;                 // ~4.06 MB

    if (ws_size >= need && d_ws != nullptr) {
        char* ws = (char*)d_ws;
        short* xh = (short*)(ws);
        short* xl = (short*)(ws + plane);
        short* yh = (short*)(ws + 2 * plane);
        short* yl = (short*)(ws + 3 * plane);
        float* xsl = (float*)(ws + 4 * plane);
        float* ysl = (float*)(ws + 4 * plane + sqsz);

        prep_kernel<<<(2 * NROWS) / 4, 256, 0, stream>>>(x, y, xh, xl, yh, yl, xsl, ysl);
        rbf_mfma_kernel<<<64 * 64, 256, 0, stream>>>(xh, xl, yh, yl, xsl, ysl, out);
    } else {
        rbf_fused_kernel<<<64 * 64, 256, 0, stream>>>(x, y, out);
    }
}